// Round 3
// baseline (245.013 us; speedup 1.0000x reference)
//
#include <hip/hip_runtime.h>
#include <math.h>

static constexpr int kM = 80;
static constexpr int kT = 4000;
static constexpr int kB = 64;
static constexpr int kLow = kM / 3;                 // 26
static constexpr int kHighStart = 2 * kM / 3;       // 53
static constexpr int kHighCount = kM - kHighStart;  // 27
static constexpr int kChunks = 25;                  // chunks per row
static constexpr int kChunkLen = kT / kChunks;      // 160 elements (40 float4)
static constexpr int kWarm = 256;                   // warm-up window: a^256 <= 2e-6 for a<=0.95
#define EPSF 1e-6f
#define LOG2E 1.4426950408889634f

typedef float vfloat4 __attribute__((ext_vector_type(4)));
typedef float vfloat2 __attribute__((ext_vector_type(2)));

// HW transcendentals: v_exp_f32 computes 2^x, v_log_f32 computes log2(x)
__device__ __forceinline__ float hw_exp2(float x) { return __builtin_amdgcn_exp2f(x); }
__device__ __forceinline__ float hw_log2(float x) { return __builtin_amdgcn_logf(x); }

__device__ __forceinline__ float fast_sigmoid(float x) {
    return __builtin_amdgcn_rcpf(1.0f + hw_exp2(-x * LOG2E));
}

// ---------------- Kernel A: gate[b,t] from cross-channel reductions ----------
// Block = 256 thr (4 waves); wave w sums channels [20w,20w+20); lane = 4 cols
// via float4. Cross-wave reduce in LDS; wave 0 finalizes. grid (16, kB) = 1024
// blocks -> 4 blocks/CU, 16 waves/CU.
__global__ __launch_bounds__(256) void gate_kernel(
    const float* __restrict__ mel,
    const float* __restrict__ gate_temp,
    float* __restrict__ gate)
{
    const int lane = threadIdx.x & 63;
    const int wid  = threadIdx.x >> 6;
    const int b    = blockIdx.y;
    const int t0   = blockIdx.x * 256 + lane * 4;
    const bool valid = (t0 < kT);

    const float* base = mel + (size_t)b * kM * kT + t0;

    vfloat4 slog = {0.f,0.f,0.f,0.f}, ssum = {0.f,0.f,0.f,0.f};
    vfloat4 slow = {0.f,0.f,0.f,0.f}, shigh = {0.f,0.f,0.f,0.f};

    const int m0 = wid * 20;
    if (valid) {
        #pragma unroll
        for (int j = 0; j < 20; ++j) {
            const int m = m0 + j;
            const vfloat4 v = *reinterpret_cast<const vfloat4*>(base + (size_t)m * kT);
            vfloat4 lg;
            lg.x = hw_log2(v.x + 1e-8f); lg.y = hw_log2(v.y + 1e-8f);
            lg.z = hw_log2(v.z + 1e-8f); lg.w = hw_log2(v.w + 1e-8f);
            slog += lg;
            ssum += v;
            if (m < kLow)        slow  += v;   // wave-uniform branch
            if (m >= kHighStart) shigh += v;
        }
    }

    __shared__ vfloat4 sh[4][4][64];   // [wid][qty][lane] = 16 KB
    sh[wid][0][lane] = slog;
    sh[wid][1][lane] = ssum;
    sh[wid][2][lane] = slow;
    sh[wid][3][lane] = shigh;
    __syncthreads();

    if (wid == 0 && valid) {
        slog  = sh[0][0][lane] + sh[1][0][lane] + sh[2][0][lane] + sh[3][0][lane];
        ssum  = sh[0][1][lane] + sh[1][1][lane] + sh[2][1][lane] + sh[3][1][lane];
        slow  = sh[0][2][lane] + sh[1][2][lane] + sh[2][2][lane] + sh[3][2][lane];
        shigh = sh[0][3][lane] + sh[1][3][lane] + sh[2][3][lane] + sh[3][3][lane];

        const float gt = gate_temp[0];
        float sl[4]  = {slog.x, slog.y, slog.z, slog.w};
        float ss[4]  = {ssum.x, ssum.y, ssum.z, ssum.w};
        float lo[4]  = {slow.x, slow.y, slow.z, slow.w};
        float hi[4]  = {shigh.x, shigh.y, shigh.z, shigh.w};
        float g4[4];
        #pragma unroll
        for (int q = 0; q < 4; ++q) {
            const float geo   = hw_exp2(sl[q] * (1.0f / kM));
            const float arith = ss[q] * (1.0f / kM) + 1e-8f;
            float sf = geo * __builtin_amdgcn_rcpf(arith);
            sf = fminf(fmaxf(sf, 0.0f), 1.0f);
            const float low  = lo[q] * (1.0f / kLow);
            const float high = hi[q] * (1.0f / kHighCount);
            float tilt = low * __builtin_amdgcn_rcpf(low + high + 1e-8f);
            tilt = fminf(fmaxf(tilt, 0.0f), 1.0f);
            const float sfa = sf + (1.0f - sf) * fmaxf(tilt - 0.6f, 0.0f);
            g4[q] = fast_sigmoid(gt * (sfa - 0.5f));
        }
        vfloat4 o; o.x = g4[0]; o.y = g4[1]; o.z = g4[2]; o.w = g4[3];
        *reinterpret_cast<vfloat4*>(gate + (size_t)b * kT + t0) = o;
    }
}

// ---------------- Kernel B: dual PCEN via truncated-history streaming --------
// s is clipped to >=0.05 so a=1-s<=0.95 and a^256 <= 2.1e-6: a thread can
// reconstruct the IIR carry by warm-starting 256 elements early with sm=0
// (error < 1e-5 at the output, 200x below the harness absmax). This removes
// the parallel scan entirely: no LDS, no barriers, no shuffles, single
// streaming pass. Thread (row, c) owns elements [c*160, c*160+160).
//   c==0: exact init sm=x[0], no warm-up.
//   c==1: exact init sm=x[0], warm-up = full history (160 elems).
//   c>=2: sm=0, warm-up 256 elems (truncation <= a^256).
// Warm-up runs as 4 independent affine segments (4-way ILP on the serial
// chain), combined with a^(seglen) powers.
__global__ __launch_bounds__(256) void pcen_kernel(
    const float* __restrict__ mel,
    const float* __restrict__ ls_ns, const float* __restrict__ la_ns,
    const float* __restrict__ ld_ns, const float* __restrict__ lr_ns,
    const float* __restrict__ ls_st, const float* __restrict__ la_st,
    const float* __restrict__ ld_st, const float* __restrict__ lr_st,
    const float* __restrict__ gate,
    float* __restrict__ out)
{
    const int row = blockIdx.x * 256 + threadIdx.x;  // 0..5119 = b*kM + m
    const int c   = blockIdx.y;                      // 0..24 (wave-uniform)
    const int b   = row / kM;
    const int m   = row - b * kM;

    const float s_ns     = fminf(fmaxf(fast_sigmoid(ls_ns[m]), 0.05f), 0.3f);
    const float alpha_ns = fminf(fmaxf(fast_sigmoid(la_ns[m]), 0.9f), 0.999f);
    const float delta_ns = fminf(fmaxf(hw_exp2(ld_ns[m] * LOG2E), 0.5f), 5.0f);
    const float r_ns     = fminf(fmaxf(fast_sigmoid(lr_ns[m]), 0.05f), 0.25f);
    const float s_st     = fminf(fmaxf(fast_sigmoid(ls_st[m]), 0.05f), 0.3f);
    const float alpha_st = fminf(fmaxf(fast_sigmoid(la_st[m]), 0.9f), 0.999f);
    const float delta_st = fminf(fmaxf(hw_exp2(ld_st[m] * LOG2E), 0.001f), 0.1f);
    const float r_st     = fminf(fmaxf(fast_sigmoid(lr_st[m]), 0.05f), 0.25f);
    const float dr_ns = hw_exp2(r_ns * hw_log2(delta_ns));   // delta^r
    const float dr_st = hw_exp2(r_st * hw_log2(delta_st));

    const vfloat2 a2 = {1.0f - s_ns, 1.0f - s_st};
    const vfloat2 s2 = {s_ns, s_st};
    const vfloat2 d2 = {delta_ns, delta_st};
    const float man = -alpha_ns, mas = -alpha_st;

    const size_t rowoff = (size_t)row * kT;
    const float* rowp = mel + rowoff;
    const int t0 = c * kChunkLen;

    // ---- establish carry sm = smoothed value just before t0 ----
    vfloat2 sm = {0.0f, 0.0f};
    if (c == 0) {
        const float x0 = rowp[0];
        sm.x = x0; sm.y = x0;                 // reference: carry init = x[0]
    } else {
        if (c == 1) {                          // full-history warm-up: exact
            const float x0 = rowp[0];
            sm.x = x0; sm.y = x0;
        }
        const int tw = (c == 1) ? 0 : (t0 - kWarm);
        const int nw = (c == 1) ? (kChunkLen / 16) : (kWarm / 16); // f4 per segment
        const float4* wp = reinterpret_cast<const float4*>(rowp + tw);

        vfloat2 B0 = {0,0}, B1 = {0,0}, B2 = {0,0}, B3 = {0,0};
        #pragma unroll 2
        for (int i = 0; i < nw; ++i) {
            const float4 v0 = wp[i];
            const float4 v1 = wp[nw + i];
            const float4 v2 = wp[2*nw + i];
            const float4 v3 = wp[3*nw + i];
            B0 = a2 * B0 + s2 * v0.x; B0 = a2 * B0 + s2 * v0.y;
            B0 = a2 * B0 + s2 * v0.z; B0 = a2 * B0 + s2 * v0.w;
            B1 = a2 * B1 + s2 * v1.x; B1 = a2 * B1 + s2 * v1.y;
            B1 = a2 * B1 + s2 * v1.z; B1 = a2 * B1 + s2 * v1.w;
            B2 = a2 * B2 + s2 * v2.x; B2 = a2 * B2 + s2 * v2.y;
            B2 = a2 * B2 + s2 * v2.z; B2 = a2 * B2 + s2 * v2.w;
            B3 = a2 * B3 + s2 * v3.x; B3 = a2 * B3 + s2 * v3.y;
            B3 = a2 * B3 + s2 * v3.z; B3 = a2 * B3 + s2 * v3.w;
        }
        // segment-combine: ps = a^(4*nw); sm = ps^4*sm + (((B0*ps+B1)*ps+B2)*ps+B3)
        const vfloat2 p2  = a2  * a2;
        const vfloat2 p4  = p2  * p2;
        const vfloat2 p8  = p4  * p4;
        const vfloat2 p16 = p8  * p8;
        const vfloat2 p32 = p16 * p16;
        const vfloat2 p64 = p32 * p32;
        const vfloat2 ps  = (c == 1) ? (p32 * p8) : p64;   // a^40 or a^64
        const vfloat2 ps2 = ps * ps;
        const vfloat2 ps4 = ps2 * ps2;
        sm = ps4 * sm + (((B0 * ps + B1) * ps + B2) * ps + B3);
    }

    // ---- streaming main pass over the owned chunk ----
    const float4* xp = reinterpret_cast<const float4*>(rowp + t0);
    const float4* gp = reinterpret_cast<const float4*>(gate + (size_t)b * kT + t0);
    float4* op = reinterpret_cast<float4*>(out + rowoff + t0);

    #pragma unroll 4
    for (int i = 0; i < kChunkLen / 4; ++i) {
        const float4 xv = xp[i];
        const float4 gg = gp[i];
        float4 o;
        #pragma unroll
        for (int j = 0; j < 4; ++j) {
            const float x1 = (&xv.x)[j];
            sm = a2 * sm + s2 * x1;            // v_pk_fma_f32
            vfloat2 g2;
            g2.x = hw_exp2(man * hw_log2(sm.x + EPSF));
            g2.y = hw_exp2(mas * hw_log2(sm.y + EPSF));
            const vfloat2 u2 = g2 * x1 + d2;   // v_pk_fma_f32
            const float on = hw_exp2(r_ns * hw_log2(u2.x)) - dr_ns;
            const float os = hw_exp2(r_st * hw_log2(u2.y)) - dr_st;
            (&o.x)[j] = fmaf((&gg.x)[j], os - on, on);
        }
        op[i] = o;                              // plain cached stores
    }
}

extern "C" void kernel_launch(void* const* d_in, const int* in_sizes, int n_in,
                              void* d_out, int out_size, void* d_ws, size_t ws_size,
                              hipStream_t stream)
{
    const float* mel       = (const float*)d_in[0];
    const float* ls_ns     = (const float*)d_in[1];
    const float* la_ns     = (const float*)d_in[2];
    const float* ld_ns     = (const float*)d_in[3];
    const float* lr_ns     = (const float*)d_in[4];
    const float* ls_st     = (const float*)d_in[5];
    const float* la_st     = (const float*)d_in[6];
    const float* ld_st     = (const float*)d_in[7];
    const float* lr_st     = (const float*)d_in[8];
    const float* gate_temp = (const float*)d_in[9];
    float* out  = (float*)d_out;
    float* gate = (float*)d_ws;   // kB*kT floats = 1.02 MB scratch

    dim3 gA(16, kB);                     // 1024 blocks, 4 waves each
    gate_kernel<<<gA, 256, 0, stream>>>(mel, gate_temp, gate);

    dim3 gB(kB * kM / 256, kChunks);     // (20, 25) = 500 blocks, 2000 waves
    pcen_kernel<<<gB, 256, 0, stream>>>(mel, ls_ns, la_ns, ld_ns, lr_ns,
                                        ls_st, la_st, ld_st, lr_st, gate, out);
}

// Round 4
// 220.137 us; speedup vs baseline: 1.1130x; 1.1130x over previous
//
#include <hip/hip_runtime.h>
#include <math.h>

static constexpr int kM = 80;
static constexpr int kT = 4000;
static constexpr int kB = 64;
static constexpr int kLow = kM / 3;                 // 26
static constexpr int kHighStart = 2 * kM / 3;       // 53
static constexpr int kHighCount = kM - kHighStart;  // 27
static constexpr int kWarm = 192;                   // a^192 <= 5.1e-5 (a<=0.95) -> out err ~6e-6
static constexpr int kLdsWords = kT + kT / 16;      // skew W = w + (w>>4): 4250 words = 17 KB
#define EPSF 1e-6f
#define LOG2E 1.4426950408889634f

typedef float vfloat4 __attribute__((ext_vector_type(4)));
typedef float vfloat2 __attribute__((ext_vector_type(2)));

__device__ __forceinline__ float hw_exp2(float x) { return __builtin_amdgcn_exp2f(x); }
__device__ __forceinline__ float hw_log2(float x) { return __builtin_amdgcn_logf(x); }

__device__ __forceinline__ float fast_sigmoid(float x) {
    return __builtin_amdgcn_rcpf(1.0f + hw_exp2(-x * LOG2E));
}

// Skewed LDS word index: stride-16 lane access maps to stride-17 mod 32
// -> all 32 banks distinct for lanes 0..31; lane l and l+32 pair = 2-way
// (free per m136). 4B-aligned ops only (b32).
__device__ __forceinline__ int skw(int w) { return w + (w >> 4); }

// ---------------- Kernel A: gate[b,t] — wave-independent column streaming ----
// Thread owns one float2 column; loops all 80 channels with stride kT.
// Per m-step a wave loads 64 lanes x 8 B = 512 B contiguous (coalesced).
// 80 independent loads pipeline under #pragma unroll. No LDS, no barriers,
// no idle waves. grid (8, 64) = 512 blocks, 2 blocks/CU.
__global__ __launch_bounds__(256) void gate_kernel(
    const float* __restrict__ mel,
    const float* __restrict__ gate_temp,
    float* __restrict__ gate)
{
    const int b  = blockIdx.y;
    const int tc = blockIdx.x * 256 + threadIdx.x;   // float2 column index
    if (tc >= kT / 2) return;

    const float* base = mel + (size_t)b * kM * kT + (size_t)tc * 2;

    vfloat2 slog = {0.f, 0.f}, ssum = {0.f, 0.f};
    vfloat2 slow = {0.f, 0.f}, shigh = {0.f, 0.f};

    #pragma unroll 16
    for (int m = 0; m < kM; ++m) {
        const vfloat2 v = *reinterpret_cast<const vfloat2*>(base + (size_t)m * kT);
        vfloat2 lg;
        lg.x = hw_log2(v.x + 1e-8f);
        lg.y = hw_log2(v.y + 1e-8f);
        slog += lg;
        ssum += v;
        if (m < kLow)        slow  += v;   // wave-uniform scalar compare
        if (m >= kHighStart) shigh += v;
    }

    const float gt = gate_temp[0];
    vfloat2 o;
    #pragma unroll
    for (int q = 0; q < 2; ++q) {
        const float sl = (q == 0) ? slog.x : slog.y;
        const float ss = (q == 0) ? ssum.x : ssum.y;
        const float lo = (q == 0) ? slow.x : slow.y;
        const float hi = (q == 0) ? shigh.x : shigh.y;
        const float geo   = hw_exp2(sl * (1.0f / kM));
        const float arith = ss * (1.0f / kM) + 1e-8f;
        float sf = geo * __builtin_amdgcn_rcpf(arith);
        sf = fminf(fmaxf(sf, 0.0f), 1.0f);
        const float low  = lo * (1.0f / kLow);
        const float high = hi * (1.0f / kHighCount);
        float tilt = low * __builtin_amdgcn_rcpf(low + high + 1e-8f);
        tilt = fminf(fmaxf(tilt, 0.0f), 1.0f);
        const float sfa = sf + (1.0f - sf) * fmaxf(tilt - 0.6f, 0.0f);
        const float g = fast_sigmoid(gt * (sfa - 0.5f));
        if (q == 0) o.x = g; else o.y = g;
    }
    *reinterpret_cast<vfloat2*>(gate + (size_t)b * kT + (size_t)tc * 2) = o;
}

// ---------------- Kernel B: dual PCEN — LDS warm-up, no scan ----------------
// Block per (b,m) row (grid 5120: proven TLP + coalescing from round 2).
// Thread owns 16 contiguous elements (coalesced float4 global loads).
// Carry reconstruction replaces the Hillis-Steele scan: stage the row in
// skewed LDS, one barrier, then each thread replays the previous kWarm=192
// elements (recurrence only, 4x48 ILP segments). s>=0.05 -> a<=0.95 ->
// truncation a^192 ~ 5e-5 -> output error ~6e-6 (absmax budget 1.95e-3).
// Threads with t0<192 replay exactly from t=0 with sm=x[0] (wave-0 only).
__global__ __launch_bounds__(256) void pcen_kernel(
    const float* __restrict__ mel,
    const float* __restrict__ ls_ns, const float* __restrict__ la_ns,
    const float* __restrict__ ld_ns, const float* __restrict__ lr_ns,
    const float* __restrict__ ls_st, const float* __restrict__ la_st,
    const float* __restrict__ ld_st, const float* __restrict__ lr_st,
    const float* __restrict__ gate,
    float* __restrict__ out)
{
    const int m = blockIdx.x;
    const int b = blockIdx.y;

    const float s_ns     = fminf(fmaxf(fast_sigmoid(ls_ns[m]), 0.05f), 0.3f);
    const float alpha_ns = fminf(fmaxf(fast_sigmoid(la_ns[m]), 0.9f), 0.999f);
    const float delta_ns = fminf(fmaxf(hw_exp2(ld_ns[m] * LOG2E), 0.5f), 5.0f);
    const float r_ns     = fminf(fmaxf(fast_sigmoid(lr_ns[m]), 0.05f), 0.25f);
    const float s_st     = fminf(fmaxf(fast_sigmoid(ls_st[m]), 0.05f), 0.3f);
    const float alpha_st = fminf(fmaxf(fast_sigmoid(la_st[m]), 0.9f), 0.999f);
    const float delta_st = fminf(fmaxf(hw_exp2(ld_st[m] * LOG2E), 0.001f), 0.1f);
    const float r_st     = fminf(fmaxf(fast_sigmoid(lr_st[m]), 0.05f), 0.25f);
    const float dr_ns = hw_exp2(r_ns * hw_log2(delta_ns));   // delta^r
    const float dr_st = hw_exp2(r_st * hw_log2(delta_st));

    const vfloat2 a2 = {1.0f - s_ns, 1.0f - s_st};
    const vfloat2 s2 = {s_ns, s_st};
    const vfloat2 d2 = {delta_ns, delta_st};
    const float man = -alpha_ns, mas = -alpha_st;

    const size_t rowoff = ((size_t)b * kM + m) * kT;
    const float* row = mel + rowoff;

    const int tid = threadIdx.x;
    const int t0  = tid * 16;
    const bool valid = (t0 < kT);   // tids 250..255 idle

    __shared__ float xs[kLdsWords];

    float x[16];
    float gv[16];
    if (valid) {
        const float4* p = reinterpret_cast<const float4*>(row + t0);
        #pragma unroll
        for (int q = 0; q < 4; ++q) {
            const float4 v = p[q];
            x[4*q+0] = v.x; x[4*q+1] = v.y; x[4*q+2] = v.z; x[4*q+3] = v.w;
        }
        // prefetch gate; latency hides under LDS stage + warm-up
        const float4* gp = reinterpret_cast<const float4*>(gate + (size_t)b * kT + t0);
        #pragma unroll
        for (int q = 0; q < 4; ++q) {
            const float4 v = gp[q];
            gv[4*q+0] = v.x; gv[4*q+1] = v.y; gv[4*q+2] = v.z; gv[4*q+3] = v.w;
        }
        // stage row into skewed LDS (conflict-free b32 writes)
        #pragma unroll
        for (int k = 0; k < 16; ++k) xs[skw(t0 + k)] = x[k];
    }
    __syncthreads();

    // ---- carry reconstruction: sm = smoothed value just before t0 ----
    vfloat2 sm = {0.0f, 0.0f};
    if (valid) {
        if (t0 >= kWarm) {
            // truncated window [t0-192, t0): 4 independent 48-long segments
            const int ws = t0 - kWarm;
            vfloat2 B0 = {0,0}, B1 = {0,0}, B2 = {0,0}, B3 = {0,0};
            #pragma unroll 4
            for (int j = 0; j < 48; ++j) {
                const float v0 = xs[skw(ws +   0 + j)];
                const float v1 = xs[skw(ws +  48 + j)];
                const float v2 = xs[skw(ws +  96 + j)];
                const float v3 = xs[skw(ws + 144 + j)];
                B0 = a2 * B0 + s2 * v0;
                B1 = a2 * B1 + s2 * v1;
                B2 = a2 * B2 + s2 * v2;
                B3 = a2 * B3 + s2 * v3;
            }
            const vfloat2 p2  = a2  * a2;
            const vfloat2 p4  = p2  * p2;
            const vfloat2 p8  = p4  * p4;
            const vfloat2 p16 = p8  * p8;
            const vfloat2 p32 = p16 * p16;
            const vfloat2 p48 = p32 * p16;      // a^48
            sm = ((B0 * p48 + B1) * p48 + B2) * p48 + B3;   // sm0 = 0 (truncated)
        } else if (t0 > 0) {
            // exact replay from t=0 (threads 1..11, wave 0 only)
            const float x0 = xs[0];             // skw(0)=0; broadcast read
            sm.x = x0; sm.y = x0;
            for (int j = 0; j < t0; ++j) {
                const float v = xs[skw(j)];
                sm = a2 * sm + s2 * v;
            }
        } else {
            // tid 0: reference carry init sm[-1] = x[0]
            sm.x = x[0]; sm.y = x[0];
        }
    }

    // ---- streaming main pass over the owned 16 elements (regs) ----
    if (valid) {
        float4* op = reinterpret_cast<float4*>(out + rowoff + t0);
        #pragma unroll
        for (int q = 0; q < 4; ++q) {
            float4 v;
            #pragma unroll
            for (int j = 0; j < 4; ++j) {
                const int k = 4*q + j;
                const float xv = x[k];
                sm = a2 * sm + s2 * xv;            // v_pk_fma_f32
                vfloat2 g2;
                g2.x = hw_exp2(man * hw_log2(sm.x + EPSF));
                g2.y = hw_exp2(mas * hw_log2(sm.y + EPSF));
                const vfloat2 u2 = g2 * xv + d2;   // v_pk_fma_f32
                const float on = hw_exp2(r_ns * hw_log2(u2.x)) - dr_ns;
                const float os = hw_exp2(r_st * hw_log2(u2.y)) - dr_st;
                (&v.x)[j] = fmaf(gv[k], os - on, on);
            }
            op[q] = v;                              // plain cached stores
        }
    }
}

extern "C" void kernel_launch(void* const* d_in, const int* in_sizes, int n_in,
                              void* d_out, int out_size, void* d_ws, size_t ws_size,
                              hipStream_t stream)
{
    const float* mel       = (const float*)d_in[0];
    const float* ls_ns     = (const float*)d_in[1];
    const float* la_ns     = (const float*)d_in[2];
    const float* ld_ns     = (const float*)d_in[3];
    const float* lr_ns     = (const float*)d_in[4];
    const float* ls_st     = (const float*)d_in[5];
    const float* la_st     = (const float*)d_in[6];
    const float* ld_st     = (const float*)d_in[7];
    const float* lr_st     = (const float*)d_in[8];
    const float* gate_temp = (const float*)d_in[9];
    float* out  = (float*)d_out;
    float* gate = (float*)d_ws;   // kB*kT floats = 1.02 MB scratch

    dim3 gA((kT / 2 + 255) / 256, kB);   // (8, 64) = 512 blocks
    gate_kernel<<<gA, 256, 0, stream>>>(mel, gate_temp, gate);

    dim3 gB(kM, kB);                     // 5120 blocks, one (b,m) row each
    pcen_kernel<<<gB, 256, 0, stream>>>(mel, ls_ns, la_ns, ld_ns, lr_ns,
                                        ls_st, la_st, ld_st, lr_st, gate, out);
}

// Round 5
// 180.059 us; speedup vs baseline: 1.3607x; 1.2226x over previous
//
#include <hip/hip_runtime.h>
#include <math.h>

static constexpr int kM = 80;
static constexpr int kT = 4000;
static constexpr int kB = 64;
static constexpr int kLow = kM / 3;                 // 26
static constexpr int kHighStart = 2 * kM / 3;       // 53
static constexpr int kHighCount = kM - kHighStart;  // 27
static constexpr int kTrunc = 12;                   // chunks of history: A_ns^12 = 0.95^192 ~ 5e-5
#define EPSF 1e-6f
#define LOG2E 1.4426950408889634f

typedef float vfloat4 __attribute__((ext_vector_type(4)));
typedef float vfloat2 __attribute__((ext_vector_type(2)));

__device__ __forceinline__ float hw_exp2(float x) { return __builtin_amdgcn_exp2f(x); }
__device__ __forceinline__ float hw_log2(float x) { return __builtin_amdgcn_logf(x); }

__device__ __forceinline__ float fast_sigmoid(float x) {
    return __builtin_amdgcn_rcpf(1.0f + hw_exp2(-x * LOG2E));
}

// ---------------- Kernel A: gate[b,t] — full-occupancy split-channel stream --
// Block = 256 thr: 128 f32 columns x 2 channel-halves (h0: m 0..39 incl. low
// band; h1: m 40..79 incl. high band). 40 coalesced loads/thread (wave =
// 64 lanes x 4 B = 256 B/instr), 3-float LDS exchange, h0 finalizes.
// grid (32, 64) = 2048 blocks x 4 waves = 8192 waves -> 32 waves/CU (max).
__global__ __launch_bounds__(256) void gate_kernel(
    const float* __restrict__ mel,
    const float* __restrict__ gate_temp,
    float* __restrict__ gate)
{
    const int tid = threadIdx.x;
    const int c   = tid & 127;          // column within group
    const int h   = tid >> 7;           // channel half (wave-uniform)
    const int b   = blockIdx.y;
    const int col = blockIdx.x * 128 + c;
    const bool valid = (col < kT);

    const float* base = mel + (size_t)b * kM * kT + col;

    float slog = 0.f, ssum = 0.f, sband = 0.f;   // sband: low (h0) / high (h1)
    if (valid) {
        if (h == 0) {
            #pragma unroll 20
            for (int m = 0; m < 40; ++m) {
                const float v = base[(size_t)m * kT];
                slog += hw_log2(v + 1e-8f);
                ssum += v;
                if (m < kLow) sband += v;              // compile-time after unroll
            }
        } else {
            #pragma unroll 20
            for (int m = 40; m < 80; ++m) {
                const float v = base[(size_t)m * kT];
                slog += hw_log2(v + 1e-8f);
                ssum += v;
                if (m >= kHighStart) sband += v;
            }
        }
    }

    __shared__ float p1[3][128];        // h1 partials: slog, ssum, shigh
    if (h == 1) {
        p1[0][c] = slog; p1[1][c] = ssum; p1[2][c] = sband;
    }
    __syncthreads();

    if (h == 0 && valid) {
        const float tlog  = slog + p1[0][c];
        const float tsum  = ssum + p1[1][c];
        const float thigh = p1[2][c];
        const float tlow  = sband;

        const float gt = gate_temp[0];
        const float geo   = hw_exp2(tlog * (1.0f / kM));
        const float arith = tsum * (1.0f / kM) + 1e-8f;
        float sf = geo * __builtin_amdgcn_rcpf(arith);
        sf = fminf(fmaxf(sf, 0.0f), 1.0f);
        const float low  = tlow  * (1.0f / kLow);
        const float high = thigh * (1.0f / kHighCount);
        float tilt = low * __builtin_amdgcn_rcpf(low + high + 1e-8f);
        tilt = fminf(fmaxf(tilt, 0.0f), 1.0f);
        const float sfa = sf + (1.0f - sf) * fmaxf(tilt - 0.6f, 0.0f);
        gate[(size_t)b * kT + col] = fast_sigmoid(gt * (sfa - 0.5f));
    }
}

// ---------------- Kernel B: dual PCEN — chunk-B carry composition -----------
// Block per (b,m) row (grid 5120; round-2's proven coalescing + TLP).
// Thread i owns 16 contiguous elements. Carry reconstruction exploits the
// DATA-INDEPENDENT chunk transform: sm -> A*sm + B_i with A = a^16 a per-row
// constant. So carry before chunk i = sum_{k<12} A^k B_{i-1-k} (+ A^i x0
// exactly for i<=12). Cost: 1 ds_write + 12 ds_read_b64 + 12 pk_fma —
// replaces round-2's 24 serial shuffles/2 barriers and round-4's 192-step
// replay. Truncation A_ns^12 ~ 5e-5 -> output err ~1e-4 (budget 1.95e-3).
__global__ __launch_bounds__(256) void pcen_kernel(
    const float* __restrict__ mel,
    const float* __restrict__ ls_ns, const float* __restrict__ la_ns,
    const float* __restrict__ ld_ns, const float* __restrict__ lr_ns,
    const float* __restrict__ ls_st, const float* __restrict__ la_st,
    const float* __restrict__ ld_st, const float* __restrict__ lr_st,
    const float* __restrict__ gate,
    float* __restrict__ out)
{
    const int m = blockIdx.x;
    const int b = blockIdx.y;

    const float s_ns     = fminf(fmaxf(fast_sigmoid(ls_ns[m]), 0.05f), 0.3f);
    const float alpha_ns = fminf(fmaxf(fast_sigmoid(la_ns[m]), 0.9f), 0.999f);
    const float delta_ns = fminf(fmaxf(hw_exp2(ld_ns[m] * LOG2E), 0.5f), 5.0f);
    const float r_ns     = fminf(fmaxf(fast_sigmoid(lr_ns[m]), 0.05f), 0.25f);
    const float s_st     = fminf(fmaxf(fast_sigmoid(ls_st[m]), 0.05f), 0.3f);
    const float alpha_st = fminf(fmaxf(fast_sigmoid(la_st[m]), 0.9f), 0.999f);
    const float alpha_dummy = alpha_st;
    const float delta_st = fminf(fmaxf(hw_exp2(ld_st[m] * LOG2E), 0.001f), 0.1f);
    const float r_st     = fminf(fmaxf(fast_sigmoid(lr_st[m]), 0.05f), 0.25f);
    const float dr_ns = hw_exp2(r_ns * hw_log2(delta_ns));   // delta^r
    const float dr_st = hw_exp2(r_st * hw_log2(delta_st));
    (void)alpha_dummy;

    const vfloat2 a2 = {1.0f - s_ns, 1.0f - s_st};
    const vfloat2 s2 = {s_ns, s_st};
    const vfloat2 d2 = {delta_ns, delta_st};
    const float man = -alpha_ns, mas = -alpha_st;

    const size_t rowoff = ((size_t)b * kM + m) * kT;
    const float* row = mel + rowoff;

    const int i  = threadIdx.x;         // chunk index
    const int t0 = i * 16;
    const bool valid = (t0 < kT);       // tids 250..255 idle

    float x[16];
    float gv[16];
    if (valid) {
        const float4* p = reinterpret_cast<const float4*>(row + t0);
        #pragma unroll
        for (int q = 0; q < 4; ++q) {
            const float4 v = p[q];
            x[4*q+0] = v.x; x[4*q+1] = v.y; x[4*q+2] = v.z; x[4*q+3] = v.w;
        }
        // prefetch gate; latency hides under chain + compose
        const float4* gp = reinterpret_cast<const float4*>(gate + (size_t)b * kT + t0);
        #pragma unroll
        for (int q = 0; q < 4; ++q) {
            const float4 v = gp[q];
            gv[4*q+0] = v.x; gv[4*q+1] = v.y; gv[4*q+2] = v.z; gv[4*q+3] = v.w;
        }
    } else {
        #pragma unroll
        for (int k = 0; k < 16; ++k) { x[k] = 0.0f; gv[k] = 0.0f; }
    }

    __shared__ float sv0;
    if (i == 0) sv0 = x[0];

    // local chunk offset B_i (serial 16 pk_fma); transform is v -> A*v + B_i
    vfloat2 Bv = {0.0f, 0.0f};
    #pragma unroll
    for (int k = 0; k < 16; ++k) {
        Bv = a2 * Bv + s2 * x[k];       // v_pk_fma_f32
    }
    const vfloat2 p2  = a2 * a2;
    const vfloat2 p4  = p2 * p2;
    const vfloat2 p8  = p4 * p4;
    const vfloat2 A2  = p8 * p8;        // a^16 (data-independent!)

    __shared__ vfloat2 Btab[256];
    Btab[i] = Bv;                       // invalid threads write zeros (unused)
    __syncthreads();

    // carry: sm = sum_{k=0}^{11} A^k B_{i-1-k}  (+ A^i * x0 exactly if i<=12)
    vfloat2 sm = {0.0f, 0.0f};
    vfloat2 pw = {1.0f, 1.0f};
    #pragma unroll
    for (int k = 0; k < kTrunc; ++k) {
        const vfloat2 Bk = Btab[(i - 1 - k) & 255];   // masked when k>=i
        if (k < i) {
            sm = pw * Bk + sm;
            pw = pw * A2;
        }
    }
    if (i <= kTrunc) {
        const float x0 = sv0;
        const vfloat2 x02 = {x0, x0};
        sm = pw * x02 + sm;             // pw = A^i here; exact init term
    }

    // ---- streaming main pass over the owned 16 elements ----
    if (valid) {
        float4* op = reinterpret_cast<float4*>(out + rowoff + t0);
        #pragma unroll
        for (int q = 0; q < 4; ++q) {
            float4 v;
            #pragma unroll
            for (int j = 0; j < 4; ++j) {
                const int k = 4*q + j;
                const float xv = x[k];
                sm = a2 * sm + s2 * xv;            // v_pk_fma_f32
                vfloat2 g2;
                g2.x = hw_exp2(man * hw_log2(sm.x + EPSF));
                g2.y = hw_exp2(mas * hw_log2(sm.y + EPSF));
                const vfloat2 u2 = g2 * xv + d2;   // v_pk_fma_f32
                const float on = hw_exp2(r_ns * hw_log2(u2.x)) - dr_ns;
                const float os = hw_exp2(r_st * hw_log2(u2.y)) - dr_st;
                (&v.x)[j] = fmaf(gv[k], os - on, on);
            }
            op[q] = v;                              // plain cached stores
        }
    }
}

extern "C" void kernel_launch(void* const* d_in, const int* in_sizes, int n_in,
                              void* d_out, int out_size, void* d_ws, size_t ws_size,
                              hipStream_t stream)
{
    const float* mel       = (const float*)d_in[0];
    const float* ls_ns     = (const float*)d_in[1];
    const float* la_ns     = (const float*)d_in[2];
    const float* ld_ns     = (const float*)d_in[3];
    const float* lr_ns     = (const float*)d_in[4];
    const float* ls_st     = (const float*)d_in[5];
    const float* la_st     = (const float*)d_in[6];
    const float* ld_st     = (const float*)d_in[7];
    const float* lr_st     = (const float*)d_in[8];
    const float* gate_temp = (const float*)d_in[9];
    float* out  = (float*)d_out;
    float* gate = (float*)d_ws;   // kB*kT floats = 1.02 MB scratch

    dim3 gA((kT + 127) / 128, kB);       // (32, 64) = 2048 blocks -> 32 waves/CU
    gate_kernel<<<gA, 256, 0, stream>>>(mel, gate_temp, gate);

    dim3 gB(kM, kB);                     // 5120 blocks, one (b,m) row each
    pcen_kernel<<<gB, 256, 0, stream>>>(mel, ls_ns, la_ns, ld_ns, lr_ns,
                                        ls_st, la_st, ld_st, lr_st, gate, out);
}